// Round 11
// baseline (261.973 us; speedup 1.0000x reference)
//
#include <hip/hip_runtime.h>
#include <hip/hip_bf16.h>
#include <math.h>

#define E 768
#define NH 12
#define HD 64
#define NTHR 256

typedef __attribute__((ext_vector_type(8))) short bf16x8;
typedef __attribute__((ext_vector_type(4))) float f32x4;

__device__ __forceinline__ unsigned short f2bf_rne(float f) {
    unsigned int u = __float_as_uint(f);
    u += 0x7FFF + ((u >> 16) & 1);   // round-to-nearest-even
    return (unsigned short)(u >> 16);
}

__device__ __forceinline__ float bf2f(unsigned short u) {
    return __uint_as_float((unsigned)u << 16);
}

// ---------------------------------------------------------------------------
// Trilinear sample of one (b,p) point -> sampled[u*E..), bf16. (R10-verified)
// ---------------------------------------------------------------------------
__device__ __forceinline__ void sample_one(
    const float* x, const float* bcrd, const float* offs, int G,
    unsigned short* sampled, int u, int P, int fullN, int t, int tstep)
{
    int b = u / P, p = u % P;
    float gm1 = (float)(G - 1);

    float cx = bcrd[p * 3 + 0] + offs[u * 3 + 0];
    float cy = bcrd[p * 3 + 1] + offs[u * 3 + 1];
    float cz = bcrd[p * 3 + 2] + offs[u * 3 + 2];
    cx = fminf(fmaxf(cx, -1.f), 1.f);
    cy = fminf(fmaxf(cy, -1.f), 1.f);
    cz = fminf(fmaxf(cz, -1.f), 1.f);

    float ix = (cx + 1.f) * 0.5f * gm1;
    float iy = (cy + 1.f) * 0.5f * gm1;
    float iz = (cz + 1.f) * 0.5f * gm1;
    float fx = floorf(ix), fy = floorf(iy), fz = floorf(iz);
    float wx = ix - fx, wy = iy - fy, wz = iz - fz;

    int x0 = (int)fminf(fmaxf(fx,       0.f), gm1);
    int x1 = (int)fminf(fmaxf(fx + 1.f, 0.f), gm1);
    int y0 = (int)fminf(fmaxf(fy,       0.f), gm1);
    int y1 = (int)fminf(fmaxf(fy + 1.f, 0.f), gm1);
    int z0 = (int)fminf(fmaxf(fz,       0.f), gm1);
    int z1 = (int)fminf(fmaxf(fz + 1.f, 0.f), gm1);

    int tk[8];
    tk[0] = (z0 * G + y0) * G + x0;
    tk[1] = (z0 * G + y0) * G + x1;
    tk[2] = (z0 * G + y1) * G + x0;
    tk[3] = (z0 * G + y1) * G + x1;
    tk[4] = (z1 * G + y0) * G + x0;
    tk[5] = (z1 * G + y0) * G + x1;
    tk[6] = (z1 * G + y1) * G + x0;
    tk[7] = (z1 * G + y1) * G + x1;
    float wgt[8];
    wgt[0] = (1.f - wz) * (1.f - wy) * (1.f - wx);
    wgt[1] = (1.f - wz) * (1.f - wy) * wx;
    wgt[2] = (1.f - wz) * wy * (1.f - wx);
    wgt[3] = (1.f - wz) * wy * wx;
    wgt[4] = wz * (1.f - wy) * (1.f - wx);
    wgt[5] = wz * (1.f - wy) * wx;
    wgt[6] = wz * wy * (1.f - wx);
    wgt[7] = wz * wy * wx;

    const float4* xb4 = (const float4*)(x + ((size_t)b * fullN + 1) * E);
    ushort4* outp = (ushort4*)(sampled + (size_t)u * E);
    for (int c4 = t; c4 < E / 4; c4 += tstep) {
        float4 acc = {0.f, 0.f, 0.f, 0.f};
#pragma unroll
        for (int k = 0; k < 8; ++k) {
            float4 v = xb4[(size_t)tk[k] * (E / 4) + c4];
            acc.x += wgt[k] * v.x; acc.y += wgt[k] * v.y;
            acc.z += wgt[k] * v.z; acc.w += wgt[k] * v.w;
        }
        ushort4 o;
        o.x = f2bf_rne(acc.x); o.y = f2bf_rne(acc.y);
        o.z = f2bf_rne(acc.z); o.w = f2bf_rne(acc.w);
        outp[c4] = o;
    }
}

// ---------------------------------------------------------------------------
// W2 tile (R10-verified, coalesced B-staging with LDS transpose).
// ---------------------------------------------------------------------------
__device__ __forceinline__ void w2_tile(
    const float* Wkv, const float* spw, unsigned short* w2_bf,
    int n0, int k0, unsigned short* lsA, unsigned short* lsB)
{
    int t = threadIdx.x;
    int wv = t >> 6;
    int ln = t & 63;
    int wm = (wv & 1) * 32;
    int wn = (wv >> 1) * 32;

    f32x4 acc[2][2] = {};

    for (int j0 = 0; j0 < E; j0 += 32) {
#pragma unroll
        for (int rep = 0; rep < 2; ++rep) {
            int fi = t + rep * 256;
            int r = fi >> 3, c4 = fi & 7;
            float4 v = *(const float4*)(Wkv + (size_t)(n0 + r) * E + j0 + c4 * 4);
            ushort4 o;
            o.x = f2bf_rne(v.x); o.y = f2bf_rne(v.y);
            o.z = f2bf_rne(v.z); o.w = f2bf_rne(v.w);
            *(ushort4*)(lsA + r * 32 + c4 * 4) = o;
        }
        {
            int r = t >> 3, c8 = t & 7;            // 32 rows x 8 groups
            const float* sp = spw + (size_t)(j0 + r) * E + k0 + c8 * 8;
            float4 v0 = *(const float4*)(sp);
            float4 v1 = *(const float4*)(sp + 4);
            int kb = c8 * 8;
            lsB[(kb + 0) * 32 + r] = f2bf_rne(v0.x);
            lsB[(kb + 1) * 32 + r] = f2bf_rne(v0.y);
            lsB[(kb + 2) * 32 + r] = f2bf_rne(v0.z);
            lsB[(kb + 3) * 32 + r] = f2bf_rne(v0.w);
            lsB[(kb + 4) * 32 + r] = f2bf_rne(v1.x);
            lsB[(kb + 5) * 32 + r] = f2bf_rne(v1.y);
            lsB[(kb + 6) * 32 + r] = f2bf_rne(v1.z);
            lsB[(kb + 7) * 32 + r] = f2bf_rne(v1.w);
        }
        __syncthreads();

        int kq = (ln >> 4) * 8;
        int rsel = ln & 15;
        bf16x8 af[2], bfr[2];
#pragma unroll
        for (int i = 0; i < 2; ++i) {
            af[i]  = *(const bf16x8*)&lsA[(wm + i * 16 + rsel) * 32 + kq];
            bfr[i] = *(const bf16x8*)&lsB[(wn + i * 16 + rsel) * 32 + kq];
        }
#pragma unroll
        for (int i = 0; i < 2; ++i)
#pragma unroll
            for (int j = 0; j < 2; ++j)
                acc[i][j] = __builtin_amdgcn_mfma_f32_16x16x32_bf16(
                    af[i], bfr[j], acc[i][j], 0, 0, 0);
        __syncthreads();
    }

    int cr = (ln >> 4) * 4;
    int cc = ln & 15;
#pragma unroll
    for (int j = 0; j < 2; ++j) {
        int col = k0 + wn + j * 16 + cc;
#pragma unroll
        for (int i = 0; i < 2; ++i) {
#pragma unroll
            for (int r = 0; r < 4; ++r) {
                int row = n0 + wm + i * 16 + cr + r;
                w2_bf[(size_t)row * E + col] = f2bf_rne(acc[i][j][r]);
            }
        }
    }
}

// Vectorized wave dot for K==768 (R10-verified).
__device__ __forceinline__ void matvec_wave_v4(
    const float* A, const float* W, const float* bias, float* C,
    int u, int N, int ln)
{
    int m = u / N, n = u % N;
    const float4* a4 = (const float4*)(A + (size_t)m * E);
    const float4* w4 = (const float4*)(W + (size_t)n * E);
    float s = 0.f;
#pragma unroll
    for (int j = 0; j < 3; ++j) {
        float4 av = a4[ln + 64 * j];
        float4 wv = w4[ln + 64 * j];
        s += av.x * wv.x + av.y * wv.y + av.z * wv.z + av.w * wv.w;
    }
#pragma unroll
    for (int off = 32; off; off >>= 1) s += __shfl_down(s, off);
    if (ln == 0) C[u] = s + bias[n];
}

// ---------------------------------------------------------------------------
// K1 "prep" (R10-verified): sampling + W2 GEMM + q-proj + b2 + aout-init.
// ---------------------------------------------------------------------------
__global__ __launch_bounds__(256) void prep_kernel(
    const float* __restrict__ x,
    const float* __restrict__ bcrd, const float* __restrict__ offs,
    const int* __restrict__ gsize,
    const float* __restrict__ bio,
    const float* __restrict__ spw, const float* __restrict__ spb,
    const float* __restrict__ ipw, const float* __restrict__ ipb,
    const float* __restrict__ opb,
    unsigned short* __restrict__ sampled_bf, unsigned short* __restrict__ w2_bf,
    float* __restrict__ q, float* __restrict__ b2, float* __restrict__ aout,
    int B, int P, int fullN, int nb_sample, int nb_w2, int nb_q, int nb_b2)
{
    __shared__ unsigned short lsA[64 * 32];
    __shared__ unsigned short lsB[64 * 32];

    int blk = blockIdx.x;
    int t = threadIdx.x;
    int wv = t >> 6, ln = t & 63;
    const float* Wkv = ipw + (size_t)E * E;

    if (blk < nb_sample) {
        sample_one(x, bcrd, offs, *gsize, sampled_bf, blk, P, fullN, t, NTHR);
        return;
    }
    blk -= nb_sample;
    if (blk < nb_w2) {
        w2_tile(Wkv, spw, w2_bf, (blk / 12) * 64, (blk % 12) * 64, lsA, lsB);
        return;
    }
    blk -= nb_w2;
    if (blk < nb_q) {
        int u = blk * 4 + wv;
        if (u < B * E) matvec_wave_v4(bio, ipw, ipb, q, u, E, ln);
        return;
    }
    blk -= nb_q;
    if (blk < nb_b2) {
        int u = blk * 4 + wv;
        if (u < 2 * E) matvec_wave_v4(spb, Wkv, ipb + E, b2, u, 2 * E, ln);
        return;
    }
    blk -= nb_b2;
    {
        // aout[b][n] = opb[n]  (K2 atomicAdds head partials on top)
        int i = blk * NTHR + t;                 // float4 index, < B*E/4
        float4 bb = ((const float4*)opb)[i % (E / 4)];
        ((float4*)aout)[i] = bb;
    }
}

// ---------------------------------------------------------------------------
// K2 "attn_ctx_op" (R10 structure). v2: the ctxs p-loop and scores p-loop
// are specialized to compile-time P=32 and fully unrolled — R10 had them
// runtime-rolled, i.e. 32 SERIALIZED L2 round-trips per thread (the same
// class of bug that cost 911us in R5's out-proj).
// ---------------------------------------------------------------------------
__global__ __launch_bounds__(256) void attn_ctx_op(
    const float* __restrict__ q, const unsigned short* __restrict__ sampled_bf,
    const unsigned short* __restrict__ w2_bf, const float* __restrict__ b2,
    const float* __restrict__ opw, float* __restrict__ aout, int B, int P)
{
    __shared__ float q_lds[HD];
    __shared__ __align__(16) float u_lds[E];
    __shared__ float sc_lds[64];
    __shared__ float at_lds[64];
    __shared__ __align__(16) float cx_lds[E];
    __shared__ float ch_lds[HD];

    int b = blockIdx.x % B;
    int h = blockIdx.x / B;
    int t = threadIdx.x, wv = t >> 6, ln = t & 63;

    const unsigned short* W2k = w2_bf + (size_t)(h * HD) * E;
    const unsigned short* W2v = w2_bf + (size_t)(E + h * HD) * E;
    const unsigned short* smp = sampled_bf + (size_t)(b * P) * E;

    if (t < HD) q_lds[t] = q[(size_t)b * E + h * HD + t];
    __syncthreads();

    // ---- u[j] = sum_d W2k[d][j] * q[h,d]  (t<192 owns j-quad) -------------
    if (t < E / 4) {
        float4 uu = {0.f, 0.f, 0.f, 0.f};
#pragma unroll
        for (int d = 0; d < HD; ++d) {
            float qd = q_lds[d];
            ushort4 r = *(const ushort4*)(W2k + (size_t)d * E + 4 * t);
            uu.x += qd * bf2f(r.x); uu.y += qd * bf2f(r.y);
            uu.z += qd * bf2f(r.z); uu.w += qd * bf2f(r.w);
        }
        *(float4*)&u_lds[4 * t] = uu;
    }
    __syncthreads();

    // ---- scores: wave wv handles p = wv + 4*pp (unrolled for P=32) --------
    if (P == 32) {
#pragma unroll
        for (int pp = 0; pp < 8; ++pp) {
            int p = wv + pp * 4;
            const unsigned short* sr = smp + (size_t)p * E;
            float s = 0.f;
#pragma unroll
            for (int c = 0; c < E / 64; ++c)
                s += u_lds[ln + 64 * c] * bf2f(sr[ln + 64 * c]);
#pragma unroll
            for (int off = 32; off; off >>= 1) s += __shfl_xor(s, off);
            if (ln == 0) sc_lds[p] = s * 0.125f;
        }
    } else {
        for (int p = wv; p < P; p += 4) {
            const unsigned short* sr = smp + (size_t)p * E;
            float s = 0.f;
#pragma unroll
            for (int c = 0; c < E / 64; ++c)
                s += u_lds[ln + 64 * c] * bf2f(sr[ln + 64 * c]);
#pragma unroll
            for (int off = 32; off; off >>= 1) s += __shfl_xor(s, off);
            if (ln == 0) sc_lds[p] = s * 0.125f;
        }
    }
    __syncthreads();

    // ---- softmax over P (wave 0) ------------------------------------------
    if (wv == 0) {
        float s = (ln < P) ? sc_lds[ln] : -INFINITY;
        float mx = s;
#pragma unroll
        for (int off = 32; off; off >>= 1) mx = fmaxf(mx, __shfl_xor(mx, off));
        float ex = (ln < P) ? __expf(s - mx) : 0.f;
        float den = ex;
#pragma unroll
        for (int off = 32; off; off >>= 1) den += __shfl_xor(den, off);
        if (ln < P) at_lds[ln] = ex / den;
    }
    __syncthreads();

    // ---- ctxs[j] = sum_p attn[p] * smp[p][j]  (t<192; P=32 unrolled) ------
    if (t < E / 4) {
        float4 cc = {0.f, 0.f, 0.f, 0.f};
        if (P == 32) {
#pragma unroll
            for (int p = 0; p < 32; ++p) {       // 32 independent L2 loads
                float a = at_lds[p];
                ushort4 r = *(const ushort4*)(smp + (size_t)p * E + 4 * t);
                cc.x += a * bf2f(r.x); cc.y += a * bf2f(r.y);
                cc.z += a * bf2f(r.z); cc.w += a * bf2f(r.w);
            }
        } else {
            for (int p = 0; p < P; ++p) {
                float a = at_lds[p];
                ushort4 r = *(const ushort4*)(smp + (size_t)p * E + 4 * t);
                cc.x += a * bf2f(r.x); cc.y += a * bf2f(r.y);
                cc.z += a * bf2f(r.z); cc.w += a * bf2f(r.w);
            }
        }
        *(float4*)&cx_lds[4 * t] = cc;
    }
    __syncthreads();

    // ---- ctx[d] = W2v[d]·ctxs + b2v[d]  (wave-dots, into LDS) -------------
    for (int d = wv; d < HD; d += 4) {
        const unsigned short* vr = W2v + (size_t)d * E;
        float s = 0.f;
#pragma unroll
        for (int c = 0; c < E / 64; ++c)
            s += cx_lds[ln + 64 * c] * bf2f(vr[ln + 64 * c]);
#pragma unroll
        for (int off = 32; off; off >>= 1) s += __shfl_down(s, off);
        if (ln == 0) ch_lds[d] = s + b2[E + h * HD + d];
    }
    __syncthreads();

    // ---- out-proj partial: thread t owns n = t, t+256, t+512 --------------
#pragma unroll
    for (int jj = 0; jj < 3; ++jj) {
        int n = t + jj * NTHR;
        const float4* wr = (const float4*)(opw + (size_t)n * E + h * HD);
        float acc = 0.f;
#pragma unroll
        for (int c = 0; c < HD / 4; ++c) {       // 16 independent 16B loads
            float4 w = wr[c];
            acc += w.x * ch_lds[4 * c] + w.y * ch_lds[4 * c + 1]
                 + w.z * ch_lds[4 * c + 2] + w.w * ch_lds[4 * c + 3];
        }
        atomicAdd(&aout[(size_t)b * E + n], acc);
    }
}

// ---------------------------------------------------------------------------
// K3 "bcast" v2: 192-thread blocks; thread t holds aout4[b][t]*conf in a
// register (one L2 load) and replicates it over ROWS_PER rows with
// back-to-back nontemporal stores. A block-wide store = 192x16B = 3072B =
// exactly one output row -> perfectly coalesced, 8 independent stores per
// thread, zero index math in the loop. Replaces R10's 1-store-per-thread +
// i%192 version (inferred ~1.8 TB/s).
// ---------------------------------------------------------------------------
#define ROWS_PER 8
__global__ __launch_bounds__(192) void bcast_kernel(
    const float* __restrict__ aout, const float* __restrict__ conf,
    float* __restrict__ out, int fullN)
{
    int b = blockIdx.y;
    int t = threadIdx.x;                       // 0..191
    f32x4 v = ((const f32x4*)(aout + (size_t)b * E))[t];
    float cf = conf[b];
    v *= cf;

    int r0 = blockIdx.x * ROWS_PER;
    int nr = fullN - r0; if (nr > ROWS_PER) nr = ROWS_PER;
    f32x4* ob = (f32x4*)(out + (size_t)b * fullN * E) + (size_t)r0 * (E / 4) + t;
#pragma unroll
    for (int r = 0; r < ROWS_PER; ++r) {
        if (r < nr) __builtin_nontemporal_store(v, ob);
        ob += E / 4;
    }
}

// ---------------------------------------------------------------------------
extern "C" void kernel_launch(void* const* d_in, const int* in_sizes, int n_in,
                              void* d_out, int out_size, void* d_ws, size_t ws_size,
                              hipStream_t stream)
{
    const float* x      = (const float*)d_in[0];
    const float* bio    = (const float*)d_in[1];
    const float* bcrd   = (const float*)d_in[2];
    const float* offs   = (const float*)d_in[3];
    const float* conf   = (const float*)d_in[4];
    const float* spw    = (const float*)d_in[5];
    const float* spb    = (const float*)d_in[6];
    const float* ipw    = (const float*)d_in[7];
    const float* ipb    = (const float*)d_in[8];
    const float* opw    = (const float*)d_in[9];
    const float* opb    = (const float*)d_in[10];
    const int*   gsize  = (const int*)d_in[11];
    float* out = (float*)d_out;

    int B     = in_sizes[1] / E;            // 64
    int P     = in_sizes[2] / 3;            // 32
    int fullN = in_sizes[0] / (B * E);      // 513
    int M     = B * P;                      // 2048

    // d_out front scratch (read by K1/K2 only; bcast overwrites all last):
    char* base = (char*)d_out;
    unsigned short* sampled_bf = (unsigned short*)(base + 0);          // 3.0 MB
    unsigned short* w2_bf      = (unsigned short*)(base + 3145728);    // 2.25 MB

    // d_ws layout (<1 MB; ws_size >= 13 MB proven):
    float* q    = (float*)d_ws;                                // 192 KB
    float* b2   = (float*)((char*)d_ws + 196608);              // 6 KB
    float* aout = (float*)((char*)d_ws + 262144);              // 192 KB

    // K1: prep (sample + W2 GEMM + q-proj + b2 + aout-init)
    int nb_sample = M;                       // 2048
    int nb_w2     = (2 * E / 64) * (E / 64); // 288
    int nb_q      = (B * E + 3) / 4;         // 12288
    int nb_b2     = (2 * E + 3) / 4;         // 384
    int nb_ai     = (B * E / 4) / NTHR;      // 48
    prep_kernel<<<nb_sample + nb_w2 + nb_q + nb_b2 + nb_ai, NTHR, 0, stream>>>(
        x, bcrd, offs, gsize, bio, spw, spb, ipw, ipb, opb,
        sampled_bf, w2_bf, q, b2, aout,
        B, P, fullN, nb_sample, nb_w2, nb_q, nb_b2);

    // K2: fused attention + out-proj partials (atomic into aout)
    attn_ctx_op<<<B * NH, NTHR, 0, stream>>>(q, sampled_bf, w2_bf, b2,
                                             opw, aout, B, P);

    // K3: broadcast * confidence (overwrites every element of d_out)
    bcast_kernel<<<dim3((fullN + ROWS_PER - 1) / ROWS_PER, B), 192, 0, stream>>>(
        aout, conf, out, fullN);
}

// Round 12
// 257.863 us; speedup vs baseline: 1.0159x; 1.0159x over previous
//
#include <hip/hip_runtime.h>
#include <hip/hip_bf16.h>
#include <math.h>

#define E 768
#define NH 12
#define HD 64
#define NTHR 256

typedef __attribute__((ext_vector_type(8))) short bf16x8;
typedef __attribute__((ext_vector_type(4))) float f32x4;

__device__ __forceinline__ unsigned short f2bf_rne(float f) {
    unsigned int u = __float_as_uint(f);
    u += 0x7FFF + ((u >> 16) & 1);   // round-to-nearest-even
    return (unsigned short)(u >> 16);
}

__device__ __forceinline__ float bf2f(unsigned short u) {
    return __uint_as_float((unsigned)u << 16);
}

// ---------------------------------------------------------------------------
// Trilinear sample of one (b,p) point -> sampled[u*E..), bf16. (R11-verified)
// ---------------------------------------------------------------------------
__device__ __forceinline__ void sample_one(
    const float* x, const float* bcrd, const float* offs, int G,
    unsigned short* sampled, int u, int P, int fullN, int t, int tstep)
{
    int b = u / P, p = u % P;
    float gm1 = (float)(G - 1);

    float cx = bcrd[p * 3 + 0] + offs[u * 3 + 0];
    float cy = bcrd[p * 3 + 1] + offs[u * 3 + 1];
    float cz = bcrd[p * 3 + 2] + offs[u * 3 + 2];
    cx = fminf(fmaxf(cx, -1.f), 1.f);
    cy = fminf(fmaxf(cy, -1.f), 1.f);
    cz = fminf(fmaxf(cz, -1.f), 1.f);

    float ix = (cx + 1.f) * 0.5f * gm1;
    float iy = (cy + 1.f) * 0.5f * gm1;
    float iz = (cz + 1.f) * 0.5f * gm1;
    float fx = floorf(ix), fy = floorf(iy), fz = floorf(iz);
    float wx = ix - fx, wy = iy - fy, wz = iz - fz;

    int x0 = (int)fminf(fmaxf(fx,       0.f), gm1);
    int x1 = (int)fminf(fmaxf(fx + 1.f, 0.f), gm1);
    int y0 = (int)fminf(fmaxf(fy,       0.f), gm1);
    int y1 = (int)fminf(fmaxf(fy + 1.f, 0.f), gm1);
    int z0 = (int)fminf(fmaxf(fz,       0.f), gm1);
    int z1 = (int)fminf(fmaxf(fz + 1.f, 0.f), gm1);

    int tk[8];
    tk[0] = (z0 * G + y0) * G + x0;
    tk[1] = (z0 * G + y0) * G + x1;
    tk[2] = (z0 * G + y1) * G + x0;
    tk[3] = (z0 * G + y1) * G + x1;
    tk[4] = (z1 * G + y0) * G + x0;
    tk[5] = (z1 * G + y0) * G + x1;
    tk[6] = (z1 * G + y1) * G + x0;
    tk[7] = (z1 * G + y1) * G + x1;
    float wgt[8];
    wgt[0] = (1.f - wz) * (1.f - wy) * (1.f - wx);
    wgt[1] = (1.f - wz) * (1.f - wy) * wx;
    wgt[2] = (1.f - wz) * wy * (1.f - wx);
    wgt[3] = (1.f - wz) * wy * wx;
    wgt[4] = wz * (1.f - wy) * (1.f - wx);
    wgt[5] = wz * (1.f - wy) * wx;
    wgt[6] = wz * wy * (1.f - wx);
    wgt[7] = wz * wy * wx;

    const float4* xb4 = (const float4*)(x + ((size_t)b * fullN + 1) * E);
    ushort4* outp = (ushort4*)(sampled + (size_t)u * E);
    for (int c4 = t; c4 < E / 4; c4 += tstep) {
        float4 acc = {0.f, 0.f, 0.f, 0.f};
#pragma unroll
        for (int k = 0; k < 8; ++k) {
            float4 v = xb4[(size_t)tk[k] * (E / 4) + c4];
            acc.x += wgt[k] * v.x; acc.y += wgt[k] * v.y;
            acc.z += wgt[k] * v.z; acc.w += wgt[k] * v.w;
        }
        ushort4 o;
        o.x = f2bf_rne(acc.x); o.y = f2bf_rne(acc.y);
        o.z = f2bf_rne(acc.z); o.w = f2bf_rne(acc.w);
        outp[c4] = o;
    }
}

// ---------------------------------------------------------------------------
// W2 tile (R11-verified, coalesced B-staging with LDS transpose).
// ---------------------------------------------------------------------------
__device__ __forceinline__ void w2_tile(
    const float* Wkv, const float* spw, unsigned short* w2_bf,
    int n0, int k0, unsigned short* lsA, unsigned short* lsB)
{
    int t = threadIdx.x;
    int wv = t >> 6;
    int ln = t & 63;
    int wm = (wv & 1) * 32;
    int wn = (wv >> 1) * 32;

    f32x4 acc[2][2] = {};

    for (int j0 = 0; j0 < E; j0 += 32) {
#pragma unroll
        for (int rep = 0; rep < 2; ++rep) {
            int fi = t + rep * 256;
            int r = fi >> 3, c4 = fi & 7;
            float4 v = *(const float4*)(Wkv + (size_t)(n0 + r) * E + j0 + c4 * 4);
            ushort4 o;
            o.x = f2bf_rne(v.x); o.y = f2bf_rne(v.y);
            o.z = f2bf_rne(v.z); o.w = f2bf_rne(v.w);
            *(ushort4*)(lsA + r * 32 + c4 * 4) = o;
        }
        {
            int r = t >> 3, c8 = t & 7;            // 32 rows x 8 groups
            const float* sp = spw + (size_t)(j0 + r) * E + k0 + c8 * 8;
            float4 v0 = *(const float4*)(sp);
            float4 v1 = *(const float4*)(sp + 4);
            int kb = c8 * 8;
            lsB[(kb + 0) * 32 + r] = f2bf_rne(v0.x);
            lsB[(kb + 1) * 32 + r] = f2bf_rne(v0.y);
            lsB[(kb + 2) * 32 + r] = f2bf_rne(v0.z);
            lsB[(kb + 3) * 32 + r] = f2bf_rne(v0.w);
            lsB[(kb + 4) * 32 + r] = f2bf_rne(v1.x);
            lsB[(kb + 5) * 32 + r] = f2bf_rne(v1.y);
            lsB[(kb + 6) * 32 + r] = f2bf_rne(v1.z);
            lsB[(kb + 7) * 32 + r] = f2bf_rne(v1.w);
        }
        __syncthreads();

        int kq = (ln >> 4) * 8;
        int rsel = ln & 15;
        bf16x8 af[2], bfr[2];
#pragma unroll
        for (int i = 0; i < 2; ++i) {
            af[i]  = *(const bf16x8*)&lsA[(wm + i * 16 + rsel) * 32 + kq];
            bfr[i] = *(const bf16x8*)&lsB[(wn + i * 16 + rsel) * 32 + kq];
        }
#pragma unroll
        for (int i = 0; i < 2; ++i)
#pragma unroll
            for (int j = 0; j < 2; ++j)
                acc[i][j] = __builtin_amdgcn_mfma_f32_16x16x32_bf16(
                    af[i], bfr[j], acc[i][j], 0, 0, 0);
        __syncthreads();
    }

    int cr = (ln >> 4) * 4;
    int cc = ln & 15;
#pragma unroll
    for (int j = 0; j < 2; ++j) {
        int col = k0 + wn + j * 16 + cc;
#pragma unroll
        for (int i = 0; i < 2; ++i) {
#pragma unroll
            for (int r = 0; r < 4; ++r) {
                int row = n0 + wm + i * 16 + cr + r;
                w2_bf[(size_t)row * E + col] = f2bf_rne(acc[i][j][r]);
            }
        }
    }
}

// Vectorized wave dot for K==768 (R11-verified).
__device__ __forceinline__ void matvec_wave_v4(
    const float* A, const float* W, const float* bias, float* C,
    int u, int N, int ln)
{
    int m = u / N, n = u % N;
    const float4* a4 = (const float4*)(A + (size_t)m * E);
    const float4* w4 = (const float4*)(W + (size_t)n * E);
    float s = 0.f;
#pragma unroll
    for (int j = 0; j < 3; ++j) {
        float4 av = a4[ln + 64 * j];
        float4 wv = w4[ln + 64 * j];
        s += av.x * wv.x + av.y * wv.y + av.z * wv.z + av.w * wv.w;
    }
#pragma unroll
    for (int off = 32; off; off >>= 1) s += __shfl_down(s, off);
    if (ln == 0) C[u] = s + bias[n];
}

// ---------------------------------------------------------------------------
// K1 "prep" (R11-verified): sampling + W2 GEMM + q-proj + b2 + aout-init.
// ---------------------------------------------------------------------------
__global__ __launch_bounds__(256) void prep_kernel(
    const float* __restrict__ x,
    const float* __restrict__ bcrd, const float* __restrict__ offs,
    const int* __restrict__ gsize,
    const float* __restrict__ bio,
    const float* __restrict__ spw, const float* __restrict__ spb,
    const float* __restrict__ ipw, const float* __restrict__ ipb,
    const float* __restrict__ opb,
    unsigned short* __restrict__ sampled_bf, unsigned short* __restrict__ w2_bf,
    float* __restrict__ q, float* __restrict__ b2, float* __restrict__ aout,
    int B, int P, int fullN, int nb_sample, int nb_w2, int nb_q, int nb_b2)
{
    __shared__ unsigned short lsA[64 * 32];
    __shared__ unsigned short lsB[64 * 32];

    int blk = blockIdx.x;
    int t = threadIdx.x;
    int wv = t >> 6, ln = t & 63;
    const float* Wkv = ipw + (size_t)E * E;

    if (blk < nb_sample) {
        sample_one(x, bcrd, offs, *gsize, sampled_bf, blk, P, fullN, t, NTHR);
        return;
    }
    blk -= nb_sample;
    if (blk < nb_w2) {
        w2_tile(Wkv, spw, w2_bf, (blk / 12) * 64, (blk % 12) * 64, lsA, lsB);
        return;
    }
    blk -= nb_w2;
    if (blk < nb_q) {
        int u = blk * 4 + wv;
        if (u < B * E) matvec_wave_v4(bio, ipw, ipb, q, u, E, ln);
        return;
    }
    blk -= nb_q;
    if (blk < nb_b2) {
        int u = blk * 4 + wv;
        if (u < 2 * E) matvec_wave_v4(spb, Wkv, ipb + E, b2, u, 2 * E, ln);
        return;
    }
    blk -= nb_b2;
    {
        // aout[b][n] = opb[n]  (K2 atomicAdds head partials on top)
        int i = blk * NTHR + t;                 // float4 index, < B*E/4
        float4 bb = ((const float4*)opb)[i % (E / 4)];
        ((float4*)aout)[i] = bb;
    }
}

// ---------------------------------------------------------------------------
// K2 "attn_ctx_op" v3: IDENTICAL math to R11, but block index is B-MAJOR:
//   h = blockIdx.x % NH, b = blockIdx.x / NH.
// Rationale [XCD locality]: block i lands on XCD i%8. With R11's h-major
// layout (h = idx/B) each h's 64 blocks spread over all 8 XCDs, so every
// XCD had to cache all 12 W2k/W2v/opw head-slices (~4.7 MB > 4 MB L2 ->
// thrash; the 64x-redundant ~300 MB W2/opw stream came from HBM/LLC).
// With b-major, XCD x sees only h in {x, x+8, x+4} mod 12 = 3 slices
// (~1.2 MB) -> L2-resident after first touch; the redundant stream becomes
// per-XCD L2 hits. smp[b] duplication across XCDs costs only ~20 MB.
// ---------------------------------------------------------------------------
__global__ __launch_bounds__(256) void attn_ctx_op(
    const float* __restrict__ q, const unsigned short* __restrict__ sampled_bf,
    const unsigned short* __restrict__ w2_bf, const float* __restrict__ b2,
    const float* __restrict__ opw, float* __restrict__ aout, int B, int P)
{
    __shared__ float q_lds[HD];
    __shared__ __align__(16) float u_lds[E];
    __shared__ float sc_lds[64];
    __shared__ float at_lds[64];
    __shared__ __align__(16) float cx_lds[E];
    __shared__ float ch_lds[HD];

    int h = blockIdx.x % NH;        // b-major: XCD sees only 3 distinct h
    int b = blockIdx.x / NH;
    int t = threadIdx.x, wv = t >> 6, ln = t & 63;

    const unsigned short* W2k = w2_bf + (size_t)(h * HD) * E;
    const unsigned short* W2v = w2_bf + (size_t)(E + h * HD) * E;
    const unsigned short* smp = sampled_bf + (size_t)(b * P) * E;

    if (t < HD) q_lds[t] = q[(size_t)b * E + h * HD + t];
    __syncthreads();

    // ---- u[j] = sum_d W2k[d][j] * q[h,d]  (t<192 owns j-quad) -------------
    if (t < E / 4) {
        float4 uu = {0.f, 0.f, 0.f, 0.f};
#pragma unroll
        for (int d = 0; d < HD; ++d) {
            float qd = q_lds[d];
            ushort4 r = *(const ushort4*)(W2k + (size_t)d * E + 4 * t);
            uu.x += qd * bf2f(r.x); uu.y += qd * bf2f(r.y);
            uu.z += qd * bf2f(r.z); uu.w += qd * bf2f(r.w);
        }
        *(float4*)&u_lds[4 * t] = uu;
    }
    __syncthreads();

    // ---- scores: wave wv handles p = wv + 4*pp (unrolled for P=32) --------
    if (P == 32) {
#pragma unroll
        for (int pp = 0; pp < 8; ++pp) {
            int p = wv + pp * 4;
            const unsigned short* sr = smp + (size_t)p * E;
            float s = 0.f;
#pragma unroll
            for (int c = 0; c < E / 64; ++c)
                s += u_lds[ln + 64 * c] * bf2f(sr[ln + 64 * c]);
#pragma unroll
            for (int off = 32; off; off >>= 1) s += __shfl_xor(s, off);
            if (ln == 0) sc_lds[p] = s * 0.125f;
        }
    } else {
        for (int p = wv; p < P; p += 4) {
            const unsigned short* sr = smp + (size_t)p * E;
            float s = 0.f;
#pragma unroll
            for (int c = 0; c < E / 64; ++c)
                s += u_lds[ln + 64 * c] * bf2f(sr[ln + 64 * c]);
#pragma unroll
            for (int off = 32; off; off >>= 1) s += __shfl_xor(s, off);
            if (ln == 0) sc_lds[p] = s * 0.125f;
        }
    }
    __syncthreads();

    // ---- softmax over P (wave 0) ------------------------------------------
    if (wv == 0) {
        float s = (ln < P) ? sc_lds[ln] : -INFINITY;
        float mx = s;
#pragma unroll
        for (int off = 32; off; off >>= 1) mx = fmaxf(mx, __shfl_xor(mx, off));
        float ex = (ln < P) ? __expf(s - mx) : 0.f;
        float den = ex;
#pragma unroll
        for (int off = 32; off; off >>= 1) den += __shfl_xor(den, off);
        if (ln < P) at_lds[ln] = ex / den;
    }
    __syncthreads();

    // ---- ctxs[j] = sum_p attn[p] * smp[p][j]  (t<192; P=32 unrolled) ------
    if (t < E / 4) {
        float4 cc = {0.f, 0.f, 0.f, 0.f};
        if (P == 32) {
#pragma unroll
            for (int p = 0; p < 32; ++p) {       // 32 independent L2 loads
                float a = at_lds[p];
                ushort4 r = *(const ushort4*)(smp + (size_t)p * E + 4 * t);
                cc.x += a * bf2f(r.x); cc.y += a * bf2f(r.y);
                cc.z += a * bf2f(r.z); cc.w += a * bf2f(r.w);
            }
        } else {
            for (int p = 0; p < P; ++p) {
                float a = at_lds[p];
                ushort4 r = *(const ushort4*)(smp + (size_t)p * E + 4 * t);
                cc.x += a * bf2f(r.x); cc.y += a * bf2f(r.y);
                cc.z += a * bf2f(r.z); cc.w += a * bf2f(r.w);
            }
        }
        *(float4*)&cx_lds[4 * t] = cc;
    }
    __syncthreads();

    // ---- ctx[d] = W2v[d]·ctxs + b2v[d]  (wave-dots, into LDS) -------------
    for (int d = wv; d < HD; d += 4) {
        const unsigned short* vr = W2v + (size_t)d * E;
        float s = 0.f;
#pragma unroll
        for (int c = 0; c < E / 64; ++c)
            s += cx_lds[ln + 64 * c] * bf2f(vr[ln + 64 * c]);
#pragma unroll
        for (int off = 32; off; off >>= 1) s += __shfl_down(s, off);
        if (ln == 0) ch_lds[d] = s + b2[E + h * HD + d];
    }
    __syncthreads();

    // ---- out-proj partial: thread t owns n = t, t+256, t+512 --------------
#pragma unroll
    for (int jj = 0; jj < 3; ++jj) {
        int n = t + jj * NTHR;
        const float4* wr = (const float4*)(opw + (size_t)n * E + h * HD);
        float acc = 0.f;
#pragma unroll
        for (int c = 0; c < HD / 4; ++c) {       // 16 independent 16B loads
            float4 w = wr[c];
            acc += w.x * ch_lds[4 * c] + w.y * ch_lds[4 * c + 1]
                 + w.z * ch_lds[4 * c + 2] + w.w * ch_lds[4 * c + 3];
        }
        atomicAdd(&aout[(size_t)b * E + n], acc);
    }
}

// ---------------------------------------------------------------------------
// K3 "bcast" (R11 version): register-replicate + NT stores.
// ---------------------------------------------------------------------------
#define ROWS_PER 8
__global__ __launch_bounds__(192) void bcast_kernel(
    const float* __restrict__ aout, const float* __restrict__ conf,
    float* __restrict__ out, int fullN)
{
    int b = blockIdx.y;
    int t = threadIdx.x;                       // 0..191
    f32x4 v = ((const f32x4*)(aout + (size_t)b * E))[t];
    float cf = conf[b];
    v *= cf;

    int r0 = blockIdx.x * ROWS_PER;
    int nr = fullN - r0; if (nr > ROWS_PER) nr = ROWS_PER;
    f32x4* ob = (f32x4*)(out + (size_t)b * fullN * E) + (size_t)r0 * (E / 4) + t;
#pragma unroll
    for (int r = 0; r < ROWS_PER; ++r) {
        if (r < nr) __builtin_nontemporal_store(v, ob);
        ob += E / 4;
    }
}

// ---------------------------------------------------------------------------
extern "C" void kernel_launch(void* const* d_in, const int* in_sizes, int n_in,
                              void* d_out, int out_size, void* d_ws, size_t ws_size,
                              hipStream_t stream)
{
    const float* x      = (const float*)d_in[0];
    const float* bio    = (const float*)d_in[1];
    const float* bcrd   = (const float*)d_in[2];
    const float* offs   = (const float*)d_in[3];
    const float* conf   = (const float*)d_in[4];
    const float* spw    = (const float*)d_in[5];
    const float* spb    = (const float*)d_in[6];
    const float* ipw    = (const float*)d_in[7];
    const float* ipb    = (const float*)d_in[8];
    const float* opw    = (const float*)d_in[9];
    const float* opb    = (const float*)d_in[10];
    const int*   gsize  = (const int*)d_in[11];
    float* out = (float*)d_out;

    int B     = in_sizes[1] / E;            // 64
    int P     = in_sizes[2] / 3;            // 32
    int fullN = in_sizes[0] / (B * E);      // 513
    int M     = B * P;                      // 2048

    // d_out front scratch (read by K1/K2 only; bcast overwrites all last):
    char* base = (char*)d_out;
    unsigned short* sampled_bf = (unsigned short*)(base + 0);          // 3.0 MB
    unsigned short* w2_bf      = (unsigned short*)(base + 3145728);    // 2.25 MB

    // d_ws layout (<1 MB; ws_size >= 13 MB proven):
    float* q    = (float*)d_ws;                                // 192 KB
    float* b2   = (float*)((char*)d_ws + 196608);              // 6 KB
    float* aout = (float*)((char*)d_ws + 262144);              // 192 KB

    // K1: prep (sample + W2 GEMM + q-proj + b2 + aout-init)
    int nb_sample = M;                       // 2048
    int nb_w2     = (2 * E / 64) * (E / 64); // 288
    int nb_q      = (B * E + 3) / 4;         // 12288
    int nb_b2     = (2 * E + 3) / 4;         // 384
    int nb_ai     = (B * E / 4) / NTHR;      // 48
    prep_kernel<<<nb_sample + nb_w2 + nb_q + nb_b2 + nb_ai, NTHR, 0, stream>>>(
        x, bcrd, offs, gsize, bio, spw, spb, ipw, ipb, opb,
        sampled_bf, w2_bf, q, b2, aout,
        B, P, fullN, nb_sample, nb_w2, nb_q, nb_b2);

    // K2: fused attention + out-proj partials (atomic into aout), b-major
    attn_ctx_op<<<B * NH, NTHR, 0, stream>>>(q, sampled_bf, w2_bf, b2,
                                             opw, aout, B, P);

    // K3: broadcast * confidence (overwrites every element of d_out)
    bcast_kernel<<<dim3((fullN + ROWS_PER - 1) / ROWS_PER, B), 192, 0, stream>>>(
        aout, conf, out, fullN);
}